// Round 1
// baseline (56.480 us; speedup 1.0000x reference)
//
#include <hip/hip_runtime.h>
#include <math.h>

// LIFNeuronFDE: fractional-order LIF with Grunwald-Letnikov memory.
//   v^{k+1} = h^beta * (I_k - v^k)/tau - sum_{j=0}^{k} c_{k+1-j} v^{(j)}
//   spike_k = sigmoid(scale * (v^{k+1} - V_th))
// Constants: tau=0.5, thresh=1.0, scale=5.0, beta=0.5, h=1.0 => h^beta=1, 1/tau=2.
// T=32, B=32, N=32768. Each (b,n) is independent -> one thread per 2 elements,
// history in registers, recurrence in fp64 (growing mode |lambda|~1.57 amplifies
// fp32 rounding ~1.6e6x over 32 steps; fp64 tracks the true trajectory).

#define T_STEPS 32
#define BN_TOTAL (32 * 32768 * 32)   // B*N = 1,048,576
#define BN (32 * 32768)              // B*N
#define PAIRS (BN / 2)               // 524,288 float2 work items

struct Coef { double c[T_STEPS + 1]; };

constexpr Coef make_coef() {
    Coef r{};
    r.c[0] = 1.0;
    double cur = 1.0;
    for (int j = 1; j <= T_STEPS; ++j) {
        cur *= (1.0 - 1.5 / (double)j);   // (1 - (1+beta)/j), beta=0.5
        r.c[j] = cur;
    }
    return r;
}

__global__ __launch_bounds__(256) void lif_fde_kernel(
    const float* __restrict__ I,
    const float* __restrict__ v0,
    float* __restrict__ out)
{
    constexpr Coef C = make_coef();

    const int idx = blockIdx.x * blockDim.x + threadIdx.x;   // [0, PAIRS)

    const float2* __restrict__ I2   = (const float2*)I;
    const float2* __restrict__ v02  = (const float2*)v0;
    float2* __restrict__       out2 = (float2*)out;

    const float2 v0f = v02[idx];
    double vx = (double)v0f.x;
    double vy = (double)v0f.y;

    double hx[T_STEPS];
    double hy[T_STEPS];

    #pragma unroll
    for (int k = 0; k < T_STEPS; ++k) {
        hx[k] = vx;
        hy[k] = vy;

        // GL memory term: sum_{j=0}^{k} c[k+1-j] * v^{(j)}
        double mx = 0.0, my = 0.0;
        #pragma unroll
        for (int j = 0; j <= k; ++j) {
            mx += C.c[k + 1 - j] * hx[j];
            my += C.c[k + 1 - j] * hy[j];
        }

        const float2 Ik = I2[(size_t)k * PAIRS + idx];

        // h^beta * (I - v)/tau - mem  with h^beta=1, 1/tau=2
        vx = 2.0 * ((double)Ik.x - vx) - mx;
        vy = 2.0 * ((double)Ik.y - vy) - my;

        // spike = sigmoid(5*(v - 1)); saturates correctly for |v| large
        const float ax = (float)(-5.0 * (vx - 1.0));
        const float ay = (float)(-5.0 * (vy - 1.0));
        const float sx = 1.0f / (1.0f + __expf(ax));
        const float sy = 1.0f / (1.0f + __expf(ay));

        out2[(size_t)k * PAIRS + idx] = make_float2(sx, sy);
    }
}

extern "C" void kernel_launch(void* const* d_in, const int* in_sizes, int n_in,
                              void* d_out, int out_size, void* d_ws, size_t ws_size,
                              hipStream_t stream) {
    const float* I  = (const float*)d_in[0];   // (T, B, N) fp32
    const float* v0 = (const float*)d_in[1];   // (B, N) fp32
    float* out = (float*)d_out;                // (T, B, N) fp32

    dim3 block(256);
    dim3 grid(PAIRS / 256);                    // 2048 blocks, exact fit
    lif_fde_kernel<<<grid, block, 0, stream>>>(I, v0, out);
}